// Round 11
// baseline (28.217 us; speedup 1.0000x reference)
//
#include <hip/hip_runtime.h>

#define E 128
#define Fb 32
#define ROWB 256   // table row byte stride (128 bf16, no pad: rows are gathered
                   // at wave-uniform rj since R2, so padding never affects banks)

__device__ inline float bf2f(unsigned short u) {
    union { unsigned int i; float f; } x;
    x.i = ((unsigned int)u) << 16;
    return x.f;
}

// monotone bijection f32 -> u32 (ascending), finite values
__device__ inline unsigned int sortable(float f) {
    union { float f; unsigned int u; } x;
    x.f = f;
    unsigned int u = x.u;
    return (u & 0x80000000u) ? ~u : (u | 0x80000000u);
}

// ------- Kernel 1: ranks (blocks 0..511) + table (blocks 512..575) ---------
// (identical to round 10)
__global__ __launch_bounds__(256) void spearman_prep(
        const float* __restrict__ de,
        unsigned char* __restrict__ ranks,
        unsigned char* __restrict__ ranksT2,
        unsigned short* __restrict__ table) {
    const int tid = threadIdx.x;

    if (blockIdx.x >= 512) {
        __shared__ float rcp[E];
        if (tid < E) rcp[tid] = 1.0f / (float)(tid + 1);
        __syncthreads();
        int idx = ((int)blockIdx.x - 512) * 256 + tid;
        int a = idx >> 7, c = idx & 127;
        float sa = 0.f, sc = 0.f, g = 0.f;
#pragma unroll 16
        for (int u = 0; u < E; ++u) {
            float wa = rcp[abs(u - a)];
            float wc = rcp[abs(u - c)];
            sa += wa;
            sc += wc;
            g += wa * wc;
        }
        float t = g - sa * sc * (1.0f / (float)(E - 1));
        union { float f; unsigned int i; } x;
        x.f = t;
        unsigned int r = (x.i + 0x7FFFu + ((x.i >> 16) & 1u)) >> 16;  // RNE bf16
        table[idx] = (unsigned short)r;
        return;
    }

    __shared__ __align__(16) unsigned char rt[8][128];  // 1 KB
    const int b = (int)blockIdx.x >> 2;
    const int q = (int)blockIdx.x & 3;
    const int wv = tid >> 6, lane = tid & 63;
    const int f0 = q * 8 + wv * 2;   // wave owns f0, f0+1

    const float2 vA = *(const float2*)(de + ((size_t)(b * E + lane)) * Fb + f0);
    const float2 vB = *(const float2*)(de + ((size_t)(b * E + lane + 64)) * Fb + f0);

    unsigned long long kA[2], kB[2];
    kA[0] = ((unsigned long long)sortable(vA.x) << 7) | (unsigned)lane;
    kA[1] = ((unsigned long long)sortable(vA.y) << 7) | (unsigned)lane;
    kB[0] = ((unsigned long long)sortable(vB.x) << 7) | (unsigned)(lane + 64);
    kB[1] = ((unsigned long long)sortable(vB.y) << 7) | (unsigned)(lane + 64);

    int c0[2] = {0, 0}, c1[2] = {0, 0};
#pragma unroll
    for (int j = 0; j < 64; ++j) {
#pragma unroll
        for (int fi = 0; fi < 2; ++fi) {
            unsigned int lo = (unsigned int)__builtin_amdgcn_readlane((int)(unsigned int)kA[fi], j);
            unsigned int hi = (unsigned int)__builtin_amdgcn_readlane((int)(unsigned int)(kA[fi] >> 32), j);
            unsigned long long cand = ((unsigned long long)hi << 32) | lo;
            c0[fi] += (int)(cand < kA[fi]);
            c1[fi] += (int)(cand < kB[fi]);
        }
    }
#pragma unroll
    for (int j = 0; j < 64; ++j) {
#pragma unroll
        for (int fi = 0; fi < 2; ++fi) {
            unsigned int lo = (unsigned int)__builtin_amdgcn_readlane((int)(unsigned int)kB[fi], j);
            unsigned int hi = (unsigned int)__builtin_amdgcn_readlane((int)(unsigned int)(kB[fi] >> 32), j);
            unsigned long long cand = ((unsigned long long)hi << 32) | lo;
            c0[fi] += (int)(cand < kA[fi]);
            c1[fi] += (int)(cand < kB[fi]);
        }
    }

#pragma unroll
    for (int fi = 0; fi < 2; ++fi) {
        rt[wv * 2 + fi][lane] = (unsigned char)c0[fi];
        rt[wv * 2 + fi][lane + 64] = (unsigned char)c1[fi];
    }
    __syncthreads();

    // coalesced dumps (ranksT2 holds rank*2 = table byte offsets)
    if (tid < 64) {
        const int f = tid >> 3, e0 = (tid & 7) * 16;   // 8 f-rows x 8 chunks
        *(uint4*)(ranks + ((size_t)b * Fb + q * 8 + f) * E + e0) = *(const uint4*)&rt[f][e0];
    }
    if (tid < 128) {
        const int e = tid;
        unsigned int w[2];
#pragma unroll
        for (int g = 0; g < 2; ++g) {
            w[g] = ((unsigned)rt[g * 4 + 0][e] * 2)
                 | (((unsigned)rt[g * 4 + 1][e] * 2) << 8)
                 | (((unsigned)rt[g * 4 + 2][e] * 2) << 16)
                 | (((unsigned)rt[g * 4 + 3][e] * 2) << 24);
        }
        *(uint2*)(ranksT2 + ((size_t)b * E + e) * Fb + q * 8) = make_uint2(w[0], w[1]);
    }
}

// ---------------- Kernel 2: out[b,j,k] = mean_f T[rj, rk], symmetric -------
// 10 tiles of 32x32 per batch covering the upper block-triangle; the 6
// off-diagonal tiles also write their transpose (lower triangle).
// 1280 blocks = exactly 5/CU (LDS = 32KB exactly). Wave w owns rows
// {j0+w+4q}; lane = (col kc=lane&31, row-half mh=lane>>5). Per gather the
// two candidate row offsets come from literal readlanes (SGPR) and one
// v_cndmask selects per lane-half -> still one ds_read_u16 per gather,
// 128 gathers/thread (-17% DS ops vs 64x32 tiling).
__global__ __launch_bounds__(256, 5) void spearman_acc(
        const unsigned char* __restrict__ ranks,
        const unsigned char* __restrict__ ranksT2,
        const unsigned short* __restrict__ table,
        float* __restrict__ out) {
    __shared__ __align__(16) char smem[E * ROWB];      // 32768 B exactly
    unsigned short* tbl = (unsigned short*)smem;       // [128][128] linear
    float* trans = (float*)smem;                       // 32*33 f32, aliases tbl
    const int tid = threadIdx.x;
    const int b = blockIdx.x / 10;
    const int t = blockIdx.x % 10;
    const int ti = (t < 4) ? 0 : (t < 7) ? 1 : (t < 9) ? 2 : 3;
    const int tj = (t < 4) ? t : (t < 7) ? t - 3 : (t < 9) ? t - 5 : 3;
    const int mir = (ti != tj);
    const int j0 = ti * 32, k0 = tj * 32;

    const int wave = tid >> 6, lane = tid & 63;
    const int kc = lane & 31;          // col within tile
    const int k = k0 + kc;
    const int mh = lane >> 5;          // row-half selector

    const unsigned char* rb  = ranks   + b * (Fb * E);
    const unsigned char* rbT = ranksT2 + b * (Fb * E);

    // column ranks (prescaled byte offsets); lane halves duplicate -> cached
    int rk2[Fb];
#pragma unroll
    for (int f4 = 0; f4 < 8; ++f4) {
        uchar4 qv = *(const uchar4*)&rbT[k * Fb + f4 * 4];
        rk2[f4 * 4 + 0] = (int)qv.x;
        rk2[f4 * 4 + 1] = (int)qv.y;
        rk2[f4 * 4 + 2] = (int)qv.z;
        rk2[f4 * 4 + 3] = (int)qv.w;
    }

    // wave-register row ranks, prescaled by row byte stride:
    // reg rp, lane l <-> (f = rp*8 + (l>>3), row = j0 + wave + 4*(l&7))
    int rj256[4];
#pragma unroll
    for (int rp = 0; rp < 4; ++rp) {
        int fl = rp * 8 + (lane >> 3);
        int row = j0 + wave + 4 * (lane & 7);
        rj256[rp] = (int)rb[fl * E + row] * ROWB;
    }

    // stage 32KB bf16 table into LDS (linear)
    const uint4* t16 = (const uint4*)table;
    uint4* d16 = (uint4*)tbl;
#pragma unroll
    for (int i = 0; i < 8; ++i) {
        int idx = tid + i * 256;
        d16[idx] = t16[idx];
    }
    __syncthreads();

    float acc[4] = {0.f, 0.f, 0.f, 0.f};
#pragma unroll
    for (int f = 0; f < Fb; ++f) {
        const int rg = f >> 3, li = (f & 7) << 3;
        const int ck = rk2[f];
#pragma unroll
        for (int m = 0; m < 4; ++m) {
            int roA = __builtin_amdgcn_readlane(rj256[rg], li | (2 * m));
            int roB = __builtin_amdgcn_readlane(rj256[rg], li | (2 * m + 1));
            int ro = mh ? roB : roA;
            acc[m] += bf2f(*(const unsigned short*)((const char*)tbl + ro + ck));
        }
    }

    const float s = 1.0f / (float)Fb;
    float* ob = out + b * (E * E);
#pragma unroll
    for (int m = 0; m < 4; ++m) {
        int row = j0 + wave + 8 * m + 4 * mh;
        ob[row * E + k] = acc[m] * s;
    }

    if (mir) {
        __syncthreads();   // all gathers done before trans overwrites tbl
#pragma unroll
        for (int m = 0; m < 4; ++m) {
            int rl = wave + 8 * m + 4 * mh;        // local row 0..31
            trans[kc * 33 + rl] = acc[m] * s;      // 2-way banks: free
        }
        __syncthreads();
        // mirror tile: out[k0+rr][j0+cc..cc+3], coalesced float4 stores
        const int rr = tid >> 3;
        const int cc = (tid & 7) * 4;
        float4 v = make_float4(trans[rr * 33 + cc + 0], trans[rr * 33 + cc + 1],
                               trans[rr * 33 + cc + 2], trans[rr * 33 + cc + 3]);
        *(float4*)&ob[(k0 + rr) * E + j0 + cc] = v;
    }
}

extern "C" void kernel_launch(void* const* d_in, const int* in_sizes, int n_in,
                              void* d_out, int out_size, void* d_ws, size_t ws_size,
                              hipStream_t stream) {
    const float* de = (const float*)d_in[0];     // [128,128,32] f32
    float* out = (float*)d_out;                  // [128,128,128] f32

    const int B = 128;
    unsigned char* ranks   = (unsigned char*)d_ws;                         // 512KB
    unsigned char* ranksT2 = (unsigned char*)d_ws + (size_t)B * Fb * E;    // 512KB
    unsigned short* table  = (unsigned short*)((char*)d_ws + 2 * (size_t)B * Fb * E);  // 32KB

    spearman_prep<<<512 + 64, 256, 0, stream>>>(de, ranks, ranksT2, table);
    spearman_acc<<<B * 10, 256, 0, stream>>>(ranks, ranksT2, table, out);
}

// Round 12
// 26.645 us; speedup vs baseline: 1.0590x; 1.0590x over previous
//
#include <hip/hip_runtime.h>

#define E 128
#define Fb 32
#define ROWB 256   // table row byte stride: 128 bf16, linear. Padding is dead:
                   // gathers use wave-uniform rows, banks depend only on rk.

__device__ inline float bf2f(unsigned short u) {
    union { unsigned int i; float f; } x;
    x.i = ((unsigned int)u) << 16;
    return x.f;
}

// monotone bijection f32 -> u32 (ascending), finite values
__device__ inline unsigned int sortable(float f) {
    union { float f; unsigned int u; } x;
    x.f = f;
    unsigned int u = x.u;
    return (u & 0x80000000u) ? ~u : (u | 0x80000000u);
}

// ------- Kernel 1: ranks (blocks 0..511) + table (blocks 512..575) ---------
// ranks: stable rank = #{j: key_j < key_e}, key = (sortable(x)<<7)|e.
//        Block = (batch b, freq-quarter q): 8 freqs; wave owns 2 freqs;
//        lane holds electrodes lane and lane+64. (identical to round 10)
// table: T[a,c] = sum_u rcp(|u-a|)*rcp(|u-c|) - S(a)S(c)/127, bf16 RNE.
__global__ __launch_bounds__(256) void spearman_prep(
        const float* __restrict__ de,
        unsigned char* __restrict__ ranks,
        unsigned char* __restrict__ ranksT2,
        unsigned short* __restrict__ table) {
    const int tid = threadIdx.x;

    if (blockIdx.x >= 512) {
        __shared__ float rcp[E];
        if (tid < E) rcp[tid] = 1.0f / (float)(tid + 1);
        __syncthreads();
        int idx = ((int)blockIdx.x - 512) * 256 + tid;
        int a = idx >> 7, c = idx & 127;
        float sa = 0.f, sc = 0.f, g = 0.f;
#pragma unroll 16
        for (int u = 0; u < E; ++u) {
            float wa = rcp[abs(u - a)];
            float wc = rcp[abs(u - c)];
            sa += wa;
            sc += wc;
            g += wa * wc;
        }
        float t = g - sa * sc * (1.0f / (float)(E - 1));
        union { float f; unsigned int i; } x;
        x.f = t;
        unsigned int r = (x.i + 0x7FFFu + ((x.i >> 16) & 1u)) >> 16;  // RNE bf16
        table[idx] = (unsigned short)r;
        return;
    }

    __shared__ __align__(16) unsigned char rt[8][128];  // 1 KB
    const int b = (int)blockIdx.x >> 2;
    const int q = (int)blockIdx.x & 3;
    const int wv = tid >> 6, lane = tid & 63;
    const int f0 = q * 8 + wv * 2;   // wave owns f0, f0+1

    const float2 vA = *(const float2*)(de + ((size_t)(b * E + lane)) * Fb + f0);
    const float2 vB = *(const float2*)(de + ((size_t)(b * E + lane + 64)) * Fb + f0);

    unsigned long long kA[2], kB[2];
    kA[0] = ((unsigned long long)sortable(vA.x) << 7) | (unsigned)lane;
    kA[1] = ((unsigned long long)sortable(vA.y) << 7) | (unsigned)lane;
    kB[0] = ((unsigned long long)sortable(vB.x) << 7) | (unsigned)(lane + 64);
    kB[1] = ((unsigned long long)sortable(vB.y) << 7) | (unsigned)(lane + 64);

    int c0[2] = {0, 0}, c1[2] = {0, 0};
#pragma unroll
    for (int j = 0; j < 64; ++j) {
#pragma unroll
        for (int fi = 0; fi < 2; ++fi) {
            unsigned int lo = (unsigned int)__builtin_amdgcn_readlane((int)(unsigned int)kA[fi], j);
            unsigned int hi = (unsigned int)__builtin_amdgcn_readlane((int)(unsigned int)(kA[fi] >> 32), j);
            unsigned long long cand = ((unsigned long long)hi << 32) | lo;
            c0[fi] += (int)(cand < kA[fi]);
            c1[fi] += (int)(cand < kB[fi]);
        }
    }
#pragma unroll
    for (int j = 0; j < 64; ++j) {
#pragma unroll
        for (int fi = 0; fi < 2; ++fi) {
            unsigned int lo = (unsigned int)__builtin_amdgcn_readlane((int)(unsigned int)kB[fi], j);
            unsigned int hi = (unsigned int)__builtin_amdgcn_readlane((int)(unsigned int)(kB[fi] >> 32), j);
            unsigned long long cand = ((unsigned long long)hi << 32) | lo;
            c0[fi] += (int)(cand < kA[fi]);
            c1[fi] += (int)(cand < kB[fi]);
        }
    }

#pragma unroll
    for (int fi = 0; fi < 2; ++fi) {
        rt[wv * 2 + fi][lane] = (unsigned char)c0[fi];
        rt[wv * 2 + fi][lane + 64] = (unsigned char)c1[fi];
    }
    __syncthreads();

    // coalesced dumps (ranksT2 holds rank*2 = table byte offsets)
    if (tid < 64) {
        const int f = tid >> 3, e0 = (tid & 7) * 16;   // 8 f-rows x 8 chunks
        *(uint4*)(ranks + ((size_t)b * Fb + q * 8 + f) * E + e0) = *(const uint4*)&rt[f][e0];
    }
    if (tid < 128) {
        const int e = tid;
        unsigned int w[2];
#pragma unroll
        for (int g = 0; g < 2; ++g) {
            w[g] = ((unsigned)rt[g * 4 + 0][e] * 2)
                 | (((unsigned)rt[g * 4 + 1][e] * 2) << 8)
                 | (((unsigned)rt[g * 4 + 2][e] * 2) << 16)
                 | (((unsigned)rt[g * 4 + 3][e] * 2) << 24);
        }
        *(uint2*)(ranksT2 + ((size_t)b * E + e) * Fb + q * 8) = make_uint2(w[0], w[1]);
    }
}

// ---------------- Kernel 2: out[b,j,k] = mean_f T[rj, rk], symmetric -------
// Round-10 structure: 6 tiles of 64 cols x 32 rows per batch covering the
// upper block-triangle at wave granularity; tiles t=1,3 also write their
// transpose. 768 blocks = 3/CU. trans aliases tbl's LDS (tbl dead after the
// gather loop; mir is block-uniform so the extra __syncthreads is legal).
__global__ __launch_bounds__(256, 4) void spearman_acc(
        const unsigned char* __restrict__ ranks,
        const unsigned char* __restrict__ ranksT2,
        const unsigned short* __restrict__ table,
        float* __restrict__ out) {
    __shared__ __align__(16) char smem[E * ROWB];      // 32768 B exactly
    unsigned short* tbl = (unsigned short*)smem;       // [128][128] linear
    float* trans = (float*)smem;                       // 64*33 f32, aliases tbl
    const int tid = threadIdx.x;
    const int b = blockIdx.x / 6;
    const int t = blockIdx.x % 6;
    const int ti  = (t < 4) ? (t >> 1) : (t - 2);   // {0,0,1,1,2,3}
    const int cb  = (t < 4) ? (t & 1) : 1;          // {0,1,0,1,1,1}
    const int mir = (t < 4) ? (t & 1) : 0;          // {0,1,0,1,0,0}
    const int j0 = ti * 32, k0 = cb * 64;

    const int wave = tid >> 6, lane = tid & 63;
    const int k = k0 + lane;
    const unsigned char* rb  = ranks   + b * (Fb * E);
    const unsigned char* rbT = ranksT2 + b * (Fb * E);

    int rk2[Fb];
#pragma unroll
    for (int f4 = 0; f4 < 8; ++f4) {
        uchar4 qv = *(const uchar4*)&rbT[k * Fb + f4 * 4];
        rk2[f4 * 4 + 0] = (int)qv.x;
        rk2[f4 * 4 + 1] = (int)qv.y;
        rk2[f4 * 4 + 2] = (int)qv.z;
        rk2[f4 * 4 + 3] = (int)qv.w;
    }

    // wave-register row ranks prescaled by row stride (x256 = shift):
    // reg rp, lane l <-> (f = rp*8 + (l>>3), row = j0 + wave + 4*(l&7))
    int rj256[4];
#pragma unroll
    for (int rp = 0; rp < 4; ++rp) {
        int fl = rp * 8 + (lane >> 3);
        int row = j0 + wave + 4 * (lane & 7);
        rj256[rp] = (int)rb[fl * E + row] << 8;
    }

    // stage 32KB bf16 table into LDS: pure linear copy
    const uint4* t16 = (const uint4*)table;
    uint4* d16 = (uint4*)tbl;
#pragma unroll
    for (int i = 0; i < 8; ++i) {
        int idx = tid + i * 256;
        d16[idx] = t16[idx];
    }
    __syncthreads();

    float acc[8] = {0.f, 0.f, 0.f, 0.f, 0.f, 0.f, 0.f, 0.f};
#pragma unroll
    for (int f = 0; f < Fb; ++f) {
        const int rg = f >> 3, li = (f & 7) << 3;
        const int ck = rk2[f];
#pragma unroll
        for (int g = 0; g < 8; ++g) {
            int ro = __builtin_amdgcn_readlane(rj256[rg], li | g);
            acc[g] += bf2f(*(const unsigned short*)((const char*)tbl + ro + ck));
        }
    }

    const float s = 1.0f / (float)Fb;
    float* ob = out + b * (E * E);
#pragma unroll
    for (int g = 0; g < 8; ++g)
        ob[(j0 + wave + 4 * g) * E + k] = acc[g] * s;   // 256B coalesced

    if (mir) {
        __syncthreads();   // all gathers done before trans overwrites tbl
#pragma unroll
        for (int g = 0; g < 8; ++g)
            trans[lane * 33 + (wave + 4 * g)] = acc[g] * s;
        __syncthreads();
        // mirror: out[k0+rr][j0+cc..cc+3]; 2 float4 ops/thread, coalesced
#pragma unroll
        for (int h = 0; h < 2; ++h) {
            const int rr = (tid >> 3) + 32 * h;    // 0..63
            const int cc = (tid & 7) * 4;          // 0..28
            float4 v = make_float4(trans[rr * 33 + cc + 0], trans[rr * 33 + cc + 1],
                                   trans[rr * 33 + cc + 2], trans[rr * 33 + cc + 3]);
            *(float4*)&ob[(k0 + rr) * E + j0 + cc] = v;
        }
    }
}

extern "C" void kernel_launch(void* const* d_in, const int* in_sizes, int n_in,
                              void* d_out, int out_size, void* d_ws, size_t ws_size,
                              hipStream_t stream) {
    const float* de = (const float*)d_in[0];     // [128,128,32] f32
    float* out = (float*)d_out;                  // [128,128,128] f32

    const int B = 128;
    unsigned char* ranks   = (unsigned char*)d_ws;                         // 512KB
    unsigned char* ranksT2 = (unsigned char*)d_ws + (size_t)B * Fb * E;    // 512KB
    unsigned short* table  = (unsigned short*)((char*)d_ws + 2 * (size_t)B * Fb * E);  // 32KB

    spearman_prep<<<512 + 64, 256, 0, stream>>>(de, ranks, ranksT2, table);
    spearman_acc<<<B * 6, 256, 0, stream>>>(ranks, ranksT2, table, out);
}

// Round 13
// 26.428 us; speedup vs baseline: 1.0677x; 1.0082x over previous
//
#include <hip/hip_runtime.h>

#define E 128
#define Fb 32
#define ROWB 256   // table row byte stride: 128 bf16, linear. Padding is dead:
                   // gathers use wave-uniform rows, banks depend only on rk.

__device__ inline float bf2f(unsigned short u) {
    union { unsigned int i; float f; } x;
    x.i = ((unsigned int)u) << 16;
    return x.f;
}

// monotone bijection f32 -> u32 (ascending), finite values
__device__ inline unsigned int sortable(float f) {
    union { float f; unsigned int u; } x;
    x.f = f;
    unsigned int u = x.u;
    return (u & 0x80000000u) ? ~u : (u | 0x80000000u);
}

// ------- Kernel 1: ranks (blocks 0..511) + table (blocks 512..575) ---------
// ranks: stable rank = #{j: key_j < key_e}, key = (sortable(x)<<7)|e.
//        Block = (batch b, freq-quarter q): 8 freqs; wave owns 2 freqs;
//        lane holds electrodes lane and lane+64. (identical to round 10)
// table: T[a,c] = sum_u rcp(|u-a|)*rcp(|u-c|) - S(a)S(c)/127, bf16 RNE.
__global__ __launch_bounds__(256) void spearman_prep(
        const float* __restrict__ de,
        unsigned char* __restrict__ ranks,
        unsigned char* __restrict__ ranksT2,
        unsigned short* __restrict__ table) {
    const int tid = threadIdx.x;

    if (blockIdx.x >= 512) {
        __shared__ float rcp[E];
        if (tid < E) rcp[tid] = 1.0f / (float)(tid + 1);
        __syncthreads();
        int idx = ((int)blockIdx.x - 512) * 256 + tid;
        int a = idx >> 7, c = idx & 127;
        float sa = 0.f, sc = 0.f, g = 0.f;
#pragma unroll 16
        for (int u = 0; u < E; ++u) {
            float wa = rcp[abs(u - a)];
            float wc = rcp[abs(u - c)];
            sa += wa;
            sc += wc;
            g += wa * wc;
        }
        float t = g - sa * sc * (1.0f / (float)(E - 1));
        union { float f; unsigned int i; } x;
        x.f = t;
        unsigned int r = (x.i + 0x7FFFu + ((x.i >> 16) & 1u)) >> 16;  // RNE bf16
        table[idx] = (unsigned short)r;
        return;
    }

    __shared__ __align__(16) unsigned char rt[8][128];  // 1 KB
    const int b = (int)blockIdx.x >> 2;
    const int q = (int)blockIdx.x & 3;
    const int wv = tid >> 6, lane = tid & 63;
    const int f0 = q * 8 + wv * 2;   // wave owns f0, f0+1

    const float2 vA = *(const float2*)(de + ((size_t)(b * E + lane)) * Fb + f0);
    const float2 vB = *(const float2*)(de + ((size_t)(b * E + lane + 64)) * Fb + f0);

    unsigned long long kA[2], kB[2];
    kA[0] = ((unsigned long long)sortable(vA.x) << 7) | (unsigned)lane;
    kA[1] = ((unsigned long long)sortable(vA.y) << 7) | (unsigned)lane;
    kB[0] = ((unsigned long long)sortable(vB.x) << 7) | (unsigned)(lane + 64);
    kB[1] = ((unsigned long long)sortable(vB.y) << 7) | (unsigned)(lane + 64);

    int c0[2] = {0, 0}, c1[2] = {0, 0};
#pragma unroll
    for (int j = 0; j < 64; ++j) {
#pragma unroll
        for (int fi = 0; fi < 2; ++fi) {
            unsigned int lo = (unsigned int)__builtin_amdgcn_readlane((int)(unsigned int)kA[fi], j);
            unsigned int hi = (unsigned int)__builtin_amdgcn_readlane((int)(unsigned int)(kA[fi] >> 32), j);
            unsigned long long cand = ((unsigned long long)hi << 32) | lo;
            c0[fi] += (int)(cand < kA[fi]);
            c1[fi] += (int)(cand < kB[fi]);
        }
    }
#pragma unroll
    for (int j = 0; j < 64; ++j) {
#pragma unroll
        for (int fi = 0; fi < 2; ++fi) {
            unsigned int lo = (unsigned int)__builtin_amdgcn_readlane((int)(unsigned int)kB[fi], j);
            unsigned int hi = (unsigned int)__builtin_amdgcn_readlane((int)(unsigned int)(kB[fi] >> 32), j);
            unsigned long long cand = ((unsigned long long)hi << 32) | lo;
            c0[fi] += (int)(cand < kA[fi]);
            c1[fi] += (int)(cand < kB[fi]);
        }
    }

#pragma unroll
    for (int fi = 0; fi < 2; ++fi) {
        rt[wv * 2 + fi][lane] = (unsigned char)c0[fi];
        rt[wv * 2 + fi][lane + 64] = (unsigned char)c1[fi];
    }
    __syncthreads();

    // coalesced dumps (ranksT2 holds rank*2 = table byte offsets)
    if (tid < 64) {
        const int f = tid >> 3, e0 = (tid & 7) * 16;   // 8 f-rows x 8 chunks
        *(uint4*)(ranks + ((size_t)b * Fb + q * 8 + f) * E + e0) = *(const uint4*)&rt[f][e0];
    }
    if (tid < 128) {
        const int e = tid;
        unsigned int w[2];
#pragma unroll
        for (int g = 0; g < 2; ++g) {
            w[g] = ((unsigned)rt[g * 4 + 0][e] * 2)
                 | (((unsigned)rt[g * 4 + 1][e] * 2) << 8)
                 | (((unsigned)rt[g * 4 + 2][e] * 2) << 16)
                 | (((unsigned)rt[g * 4 + 3][e] * 2) << 24);
        }
        *(uint2*)(ranksT2 + ((size_t)b * E + e) * Fb + q * 8) = make_uint2(w[0], w[1]);
    }
}

// ---------------- Kernel 2: out[b,j,k] = mean_f T[rj, rk], symmetric -------
// Round-10 structure: 6 tiles of 64 cols x 32 rows per batch covering the
// upper block-triangle at wave granularity; tiles t=1,3 also write their
// transpose. 768 blocks = 3/CU. trans aliases tbl's LDS (tbl dead after the
// gather loop; mir is block-uniform so the extra __syncthreads is legal).
__global__ __launch_bounds__(256, 4) void spearman_acc(
        const unsigned char* __restrict__ ranks,
        const unsigned char* __restrict__ ranksT2,
        const unsigned short* __restrict__ table,
        float* __restrict__ out) {
    __shared__ __align__(16) char smem[E * ROWB];      // 32768 B exactly
    unsigned short* tbl = (unsigned short*)smem;       // [128][128] linear
    float* trans = (float*)smem;                       // 64*33 f32, aliases tbl
    const int tid = threadIdx.x;
    const int b = blockIdx.x / 6;
    const int t = blockIdx.x % 6;
    const int ti  = (t < 4) ? (t >> 1) : (t - 2);   // {0,0,1,1,2,3}
    const int cb  = (t < 4) ? (t & 1) : 1;          // {0,1,0,1,1,1}
    const int mir = (t < 4) ? (t & 1) : 0;          // {0,1,0,1,0,0}
    const int j0 = ti * 32, k0 = cb * 64;

    const int wave = tid >> 6, lane = tid & 63;
    const int k = k0 + lane;
    const unsigned char* rb  = ranks   + b * (Fb * E);
    const unsigned char* rbT = ranksT2 + b * (Fb * E);

    int rk2[Fb];
#pragma unroll
    for (int f4 = 0; f4 < 8; ++f4) {
        uchar4 qv = *(const uchar4*)&rbT[k * Fb + f4 * 4];
        rk2[f4 * 4 + 0] = (int)qv.x;
        rk2[f4 * 4 + 1] = (int)qv.y;
        rk2[f4 * 4 + 2] = (int)qv.z;
        rk2[f4 * 4 + 3] = (int)qv.w;
    }

    // wave-register row ranks prescaled by row stride (x256 = shift):
    // reg rp, lane l <-> (f = rp*8 + (l>>3), row = j0 + wave + 4*(l&7))
    int rj256[4];
#pragma unroll
    for (int rp = 0; rp < 4; ++rp) {
        int fl = rp * 8 + (lane >> 3);
        int row = j0 + wave + 4 * (lane & 7);
        rj256[rp] = (int)rb[fl * E + row] << 8;
    }

    // stage 32KB bf16 table into LDS: pure linear copy
    const uint4* t16 = (const uint4*)table;
    uint4* d16 = (uint4*)tbl;
#pragma unroll
    for (int i = 0; i < 8; ++i) {
        int idx = tid + i * 256;
        d16[idx] = t16[idx];
    }
    __syncthreads();

    float acc[8] = {0.f, 0.f, 0.f, 0.f, 0.f, 0.f, 0.f, 0.f};
#pragma unroll
    for (int f = 0; f < Fb; ++f) {
        const int rg = f >> 3, li = (f & 7) << 3;
        const int ck = rk2[f];
#pragma unroll
        for (int g = 0; g < 8; ++g) {
            int ro = __builtin_amdgcn_readlane(rj256[rg], li | g);
            acc[g] += bf2f(*(const unsigned short*)((const char*)tbl + ro + ck));
        }
    }

    const float s = 1.0f / (float)Fb;
    float* ob = out + b * (E * E);
#pragma unroll
    for (int g = 0; g < 8; ++g)
        ob[(j0 + wave + 4 * g) * E + k] = acc[g] * s;   // 256B coalesced

    if (mir) {
        __syncthreads();   // all gathers done before trans overwrites tbl
#pragma unroll
        for (int g = 0; g < 8; ++g)
            trans[lane * 33 + (wave + 4 * g)] = acc[g] * s;
        __syncthreads();
        // mirror: out[k0+rr][j0+cc..cc+3]; 2 float4 ops/thread, coalesced
#pragma unroll
        for (int h = 0; h < 2; ++h) {
            const int rr = (tid >> 3) + 32 * h;    // 0..63
            const int cc = (tid & 7) * 4;          // 0..28
            float4 v = make_float4(trans[rr * 33 + cc + 0], trans[rr * 33 + cc + 1],
                                   trans[rr * 33 + cc + 2], trans[rr * 33 + cc + 3]);
            *(float4*)&ob[(k0 + rr) * E + j0 + cc] = v;
        }
    }
}

extern "C" void kernel_launch(void* const* d_in, const int* in_sizes, int n_in,
                              void* d_out, int out_size, void* d_ws, size_t ws_size,
                              hipStream_t stream) {
    const float* de = (const float*)d_in[0];     // [128,128,32] f32
    float* out = (float*)d_out;                  // [128,128,128] f32

    const int B = 128;
    unsigned char* ranks   = (unsigned char*)d_ws;                         // 512KB
    unsigned char* ranksT2 = (unsigned char*)d_ws + (size_t)B * Fb * E;    // 512KB
    unsigned short* table  = (unsigned short*)((char*)d_ws + 2 * (size_t)B * Fb * E);  // 32KB

    spearman_prep<<<512 + 64, 256, 0, stream>>>(de, ranks, ranksT2, table);
    spearman_acc<<<B * 6, 256, 0, stream>>>(ranks, ranksT2, table, out);
}